// Round 6
// baseline (271.031 us; speedup 1.0000x reference)
//
#include <hip/hip_runtime.h>

#define N_NODES 50000
#define D 128
#define N_EDGES 800000

typedef __attribute__((ext_vector_type(8))) short short8;
typedef __attribute__((ext_vector_type(4))) float f32x4;

__device__ __forceinline__ unsigned short f2bf(float f) {
    unsigned u = __builtin_bit_cast(unsigned, f);
    u += 0x7FFFu + ((u >> 16) & 1u);
    return (unsigned short)(u >> 16);
}
__device__ __forceinline__ float bflo(unsigned p) {
    return __builtin_bit_cast(float, p << 16);
}
__device__ __forceinline__ float bfhi(unsigned p) {
    return __builtin_bit_cast(float, p & 0xFFFF0000u);
}

#define GEMM_BLOCKS ((N_NODES + 63) / 64)   // 782
#define HIST_VBLOCKS 1024                   // virtual blocks per support

// ---- build wt[s][c][k] bf16 (transposed, c-major) from w[s][k][c] f32 ----
__global__ __launch_bounds__(256) void wt_build(const float* __restrict__ w,
                                                unsigned short* __restrict__ wt) {
    int i = blockIdx.x * 256 + threadIdx.x;
    if (i < 2 * D * D) {
        int s = i >> 14, rem = i & 16383, c = rem >> 7, k = rem & 127;
        wt[i] = f2bf(w[s * D * D + k * D + c]);
    }
}

// ---- gemm body (device fn): pre_s = bf16(x @ W_s) for 64 rows starting r0 ----
template<int NS>
__device__ __forceinline__ void gemm_body(const float* __restrict__ x,
                                          const unsigned short* __restrict__ wt,
                                          unsigned short* __restrict__ pre0,
                                          unsigned short* __restrict__ pre1,
                                          int n_rows, int blk) {
    const int lane = threadIdx.x & 63;
    const int wid  = threadIdx.x >> 6;
    const int q    = lane >> 4;
    const int rlo  = lane & 15;
    const int r0   = blk * 64 + wid * 16;
    if (r0 >= n_rows) return;

    const float4* x4 = (const float4*)x;
    int arow  = r0 + rlo;
    int arowc = arow < n_rows ? arow : n_rows - 1;

    short8 afr[4];
    #pragma unroll
    for (int kb = 0; kb < 4; ++kb) {
        float4 fa = x4[(size_t)arowc * 32 + kb * 8 + q * 2];
        float4 fb = x4[(size_t)arowc * 32 + kb * 8 + q * 2 + 1];
        short8 a;
        a[0] = (short)f2bf(fa.x); a[1] = (short)f2bf(fa.y);
        a[2] = (short)f2bf(fa.z); a[3] = (short)f2bf(fa.w);
        a[4] = (short)f2bf(fb.x); a[5] = (short)f2bf(fb.y);
        a[6] = (short)f2bf(fb.z); a[7] = (short)f2bf(fb.w);
        afr[kb] = a;
    }

    const short8* wt8 = (const short8*)wt;
    f32x4 acc[NS][8];
    #pragma unroll
    for (int s = 0; s < NS; ++s)
        #pragma unroll
        for (int t = 0; t < 8; ++t)
            acc[s][t] = (f32x4){0.f, 0.f, 0.f, 0.f};

    #pragma unroll
    for (int t = 0; t < 8; ++t) {
        int c = t * 16 + rlo;
        #pragma unroll
        for (int kb = 0; kb < 4; ++kb) {
            short8 b0 = wt8[(size_t)c * 16 + kb * 4 + q];
            acc[0][t] = __builtin_amdgcn_mfma_f32_16x16x32_bf16(afr[kb], b0, acc[0][t], 0, 0, 0);
            if (NS == 2) {
                short8 b1 = wt8[(size_t)(D + c) * 16 + kb * 4 + q];
                acc[1][t] = __builtin_amdgcn_mfma_f32_16x16x32_bf16(afr[kb], b1, acc[1][t], 0, 0, 0);
            }
        }
    }

    #pragma unroll
    for (int i = 0; i < 4; ++i) {
        int rw = r0 + q * 4 + i;
        if (rw < n_rows) {
            #pragma unroll
            for (int t = 0; t < 8; ++t) {
                pre0[(size_t)rw * D + t * 16 + rlo] = f2bf(acc[0][t][i]);
                if (NS == 2) pre1[(size_t)rw * D + t * 16 + rlo] = f2bf(acc[1][t][i]);
            }
        }
    }
}

// ---- K1: grid-fused [gemm blocks | hist blocks] (independent work, overlap) ----
__global__ __launch_bounds__(256) void k1_gemm_hist(const float* __restrict__ x,
                                                    const unsigned short* __restrict__ wt,
                                                    unsigned short* __restrict__ pre0,
                                                    unsigned short* __restrict__ pre1,
                                                    const int* __restrict__ r0,
                                                    const int* __restrict__ r1,
                                                    int* __restrict__ cnt_base,
                                                    int* __restrict__ rank_base,
                                                    int n_rows, int n_edges) {
    int bid = blockIdx.x;
    if (bid < GEMM_BLOCKS) {
        gemm_body<2>(x, wt, pre0, pre1, n_rows, bid);
    } else {
        int hb = bid - GEMM_BLOCKS;       // 0 .. 2*HIST_VBLOCKS-1
        int s  = hb & 1;
        int vb = hb >> 1;
        const int* r = s ? r1 : r0;
        int* cnt  = cnt_base + s * N_NODES;
        int* rank = rank_base + (size_t)s * N_EDGES;
        for (int e = vb * 256 + (int)threadIdx.x; e < n_edges; e += HIST_VBLOCKS * 256)
            rank[e] = atomicAdd(&cnt[r[e]], 1);
    }
}

// ---- standalone pieces for fallback paths ----
__global__ __launch_bounds__(256) void gemm_mfma1(const float* __restrict__ x,
                                                  const unsigned short* __restrict__ wt,
                                                  unsigned short* __restrict__ pre,
                                                  int n_rows) {
    gemm_body<1>(x, wt, pre, pre, n_rows, blockIdx.x);
}

__global__ __launch_bounds__(256) void hist_rank(const int* __restrict__ r0,
                                                 const int* __restrict__ r1,
                                                 int* __restrict__ cnt_base,
                                                 int* __restrict__ rank_base, int n_edges) {
    int s = blockIdx.y;
    const int* r = s ? r1 : r0;
    int* cnt  = cnt_base + s * N_NODES;
    int* rank = rank_base + (size_t)s * N_EDGES;
    for (int e = blockIdx.x * 256 + threadIdx.x; e < n_edges; e += gridDim.x * 256)
        rank[e] = atomicAdd(&cnt[r[e]], 1);
}

// ---- fast exclusive scan: thread-local sums + one block scan + prefix write ----
// blockIdx.x = support. CH elements per thread.
__global__ __launch_bounds__(1024) void scan_fast(const int* __restrict__ counts_base,
                                                  int* __restrict__ offsets_base, int n) {
    const int CH = (N_NODES + 1023) / 1024;   // 49
    const int* counts = counts_base + blockIdx.x * n;
    int* offsets      = offsets_base + blockIdx.x * (n + 1);
    const int t    = threadIdx.x;
    const int lane = t & 63;
    const int wid  = t >> 6;
    const int base = t * CH;

    int local = 0;
    #pragma unroll 4
    for (int i = 0; i < CH; ++i) {
        int idx = base + i;
        if (idx < n) local += counts[idx];
    }
    // block exclusive scan of `local`
    __shared__ int wsum[16];
    int incl = local;
    #pragma unroll
    for (int off = 1; off < 64; off <<= 1) {
        int tv = __shfl_up(incl, off);
        if (lane >= off) incl += tv;
    }
    if (lane == 63) wsum[wid] = incl;
    __syncthreads();
    if (wid == 0 && lane < 16) {
        int wv = wsum[lane];
        int wi = wv;
        #pragma unroll
        for (int off = 1; off < 16; off <<= 1) {
            int tv = __shfl_up(wi, off);
            if (lane >= off) wi += tv;
        }
        wsum[lane] = wi - wv;
    }
    __syncthreads();
    int running = (incl - local) + wsum[wid];
    #pragma unroll 4
    for (int i = 0; i < CH; ++i) {
        int idx = base + i;
        if (idx < n) {
            offsets[idx] = running;
            running += counts[idx];
        }
    }
    if (t == 1023) offsets[n] = running;   // thread 1023's base >= n ⇒ running == total
}

// ---- CSR scatter: no atomics, fire-and-forget 8B stores (y-dim = support) ----
__global__ __launch_bounds__(256) void scatter_csr(const int* __restrict__ r0, const int* __restrict__ c0,
                                                   const float* __restrict__ v0,
                                                   const int* __restrict__ r1, const int* __restrict__ c1,
                                                   const float* __restrict__ v1,
                                                   const int* __restrict__ off_base,
                                                   const int* __restrict__ rank_base,
                                                   int2* __restrict__ ep_base, int n_edges) {
    int s = blockIdx.y;
    const int*   r    = s ? r1 : r0;
    const int*   c    = s ? c1 : c0;
    const float* v    = s ? v1 : v0;
    const int*   off  = off_base + s * (N_NODES + 1);
    const int*   rank = rank_base + (size_t)s * N_EDGES;
    int2* ep = ep_base + (size_t)s * N_EDGES;
    for (int e = blockIdx.x * 256 + threadIdx.x; e < n_edges; e += gridDim.x * 256) {
        int p = off[r[e]] + rank[e];
        int2 rec;
        rec.x = c[e];
        rec.y = __float_as_int(v[e]);
        ep[p] = rec;
    }
}

// ---- row accumulate: unroll-8 pipelined random reads ----
__device__ __forceinline__ void row_acc(const int2* __restrict__ ep,
                                        const unsigned short* __restrict__ pre,
                                        int b, int e, int lane, float& ax, float& ay) {
    int i = b;
    for (; i + 7 < e; i += 8) {
        int2 E[8];
        unsigned P[8];
        #pragma unroll
        for (int j = 0; j < 8; ++j) E[j] = ep[i + j];
        #pragma unroll
        for (int j = 0; j < 8; ++j) P[j] = *(const unsigned*)(pre + (size_t)E[j].x * D + 2 * lane);
        #pragma unroll
        for (int j = 0; j < 8; ++j) {
            float w = __int_as_float(E[j].y);
            ax = fmaf(w, bflo(P[j]), ax);
            ay = fmaf(w, bfhi(P[j]), ay);
        }
    }
    if (i + 3 < e) {
        int2 E[4];
        unsigned P[4];
        #pragma unroll
        for (int j = 0; j < 4; ++j) E[j] = ep[i + j];
        #pragma unroll
        for (int j = 0; j < 4; ++j) P[j] = *(const unsigned*)(pre + (size_t)E[j].x * D + 2 * lane);
        #pragma unroll
        for (int j = 0; j < 4; ++j) {
            float w = __int_as_float(E[j].y);
            ax = fmaf(w, bflo(P[j]), ax);
            ay = fmaf(w, bfhi(P[j]), ay);
        }
        i += 4;
    }
    for (; i < e; ++i) {
        int2 e0 = ep[i];
        float w = __int_as_float(e0.y);
        unsigned p = *(const unsigned*)(pre + (size_t)e0.x * D + 2 * lane);
        ax = fmaf(w, bflo(p), ax);
        ay = fmaf(w, bfhi(p), ay);
    }
}

// ---- fused gather: out = relu(A0@pre0 + A1@pre1), one wave per row ----
__global__ __launch_bounds__(256) void gather_fused(const int* __restrict__ off_base,
                                                    const int2* __restrict__ ep_base,
                                                    const unsigned short* __restrict__ pre0,
                                                    const unsigned short* __restrict__ pre1,
                                                    float* __restrict__ out, int n_rows) {
    const int lane = threadIdx.x & 63;
    const int wid  = threadIdx.x >> 6;
    const int wpg  = 4 * gridDim.x;
    float2* out2 = (float2*)out;
    for (int r = blockIdx.x * 4 + wid; r < n_rows; r += wpg) {
        float ax0 = 0.f, ay0 = 0.f, ax1 = 0.f, ay1 = 0.f;
        row_acc(ep_base, pre0, off_base[r], off_base[r + 1], lane, ax0, ay0);
        const int* o1 = off_base + (N_NODES + 1);
        row_acc(ep_base + N_EDGES, pre1, o1[r], o1[r + 1], lane, ax1, ay1);
        float2 o;
        o.x = fmaxf(ax0 + ax1, 0.f);
        o.y = fmaxf(ay0 + ay1, 0.f);
        out2[(size_t)r * 64 + lane] = o;
    }
}

// ---- single-support gather (sequential fallback) ----
template<int ACCUM_RELU>
__global__ __launch_bounds__(256) void gather_one(const int* __restrict__ off,
                                                  const int2* __restrict__ ep,
                                                  const unsigned short* __restrict__ pre,
                                                  float* __restrict__ out, int n_rows) {
    const int lane = threadIdx.x & 63;
    const int wid  = threadIdx.x >> 6;
    const int wpg  = 4 * gridDim.x;
    float2* out2 = (float2*)out;
    for (int r = blockIdx.x * 4 + wid; r < n_rows; r += wpg) {
        float ax = 0.f, ay = 0.f;
        row_acc(ep, pre, off[r], off[r + 1], lane, ax, ay);
        float2 o;
        if (ACCUM_RELU) {
            float2 prev = out2[(size_t)r * 64 + lane];
            o.x = fmaxf(prev.x + ax, 0.f);
            o.y = fmaxf(prev.y + ay, 0.f);
        } else {
            o.x = ax; o.y = ay;
        }
        out2[(size_t)r * 64 + lane] = o;
    }
}

extern "C" void kernel_launch(void* const* d_in, const int* in_sizes, int n_in,
                              void* d_out, int out_size, void* d_ws, size_t ws_size,
                              hipStream_t stream) {
    const float* x       = (const float*)d_in[0];
    const float* weights = (const float*)d_in[1];
    const int*   ei0     = (const int*)d_in[2];
    const float* v0      = (const float*)d_in[3];
    const int*   ei1     = (const int*)d_in[4];
    const float* v1      = (const float*)d_in[5];
    float* out = (float*)d_out;

    dim3 blk(256);
    const size_t PRE_B = (size_t)N_NODES * D * sizeof(unsigned short);  // 12.8 MB
    const size_t WT_B  = (size_t)2 * D * D * sizeof(unsigned short);    // 64 KB

    char* wsb = (char*)d_ws;
    // tier A: pre0, pre1, wt, off[2(N+1)], cnt[2N], ep[2E], rank[2E]
    size_t needA = PRE_B * 2 + WT_B + (size_t)(2 * (N_NODES + 1) + 2 * N_NODES) * 4
                 + (size_t)2 * N_EDGES * sizeof(int2) + (size_t)2 * N_EDGES * 4;
    // tier B: same minus rank (rank aliases pre0, serial schedule)
    size_t needB = needA - (size_t)2 * N_EDGES * 4;

    if (ws_size >= needA) {
        unsigned short* pre0 = (unsigned short*)wsb;
        unsigned short* pre1 = (unsigned short*)(wsb + PRE_B);
        unsigned short* wt   = (unsigned short*)(wsb + 2 * PRE_B);
        int*  off  = (int*)(wsb + 2 * PRE_B + WT_B);
        int*  cnt  = off + 2 * (N_NODES + 1);
        int2* ep   = (int2*)(cnt + 2 * N_NODES);
        int*  rank = (int*)(ep + (size_t)2 * N_EDGES);

        hipMemsetAsync(cnt, 0, (size_t)2 * N_NODES * sizeof(int), stream);
        wt_build<<<128, blk, 0, stream>>>(weights, wt);
        // overlapped: gemm blocks first, hist blocks backfill
        k1_gemm_hist<<<GEMM_BLOCKS + 2 * HIST_VBLOCKS, blk, 0, stream>>>(
            x, wt, pre0, pre1, ei0, ei1, cnt, rank, N_NODES, N_EDGES);
        scan_fast<<<2, 1024, 0, stream>>>(cnt, off, N_NODES);
        scatter_csr<<<dim3(1024, 2), blk, 0, stream>>>(ei0, ei0 + N_EDGES, v0,
                                                       ei1, ei1 + N_EDGES, v1,
                                                       off, rank, ep, N_EDGES);
        gather_fused<<<12500, blk, 0, stream>>>(off, ep, pre0, pre1, out, N_NODES);
    } else if (ws_size >= needB) {
        unsigned short* pre0 = (unsigned short*)wsb;
        unsigned short* pre1 = (unsigned short*)(wsb + PRE_B);
        unsigned short* wt   = (unsigned short*)(wsb + 2 * PRE_B);
        int*  off  = (int*)(wsb + 2 * PRE_B + WT_B);
        int*  cnt  = off + 2 * (N_NODES + 1);
        int2* ep   = (int2*)(cnt + 2 * N_NODES);
        int*  rank = (int*)pre0;   // aliases pre0; serial: scatter before gemm

        hipMemsetAsync(cnt, 0, (size_t)2 * N_NODES * sizeof(int), stream);
        wt_build<<<128, blk, 0, stream>>>(weights, wt);
        hist_rank<<<dim3(1024, 2), blk, 0, stream>>>(ei0, ei1, cnt, rank, N_EDGES);
        scan_fast<<<2, 1024, 0, stream>>>(cnt, off, N_NODES);
        scatter_csr<<<dim3(1024, 2), blk, 0, stream>>>(ei0, ei0 + N_EDGES, v0,
                                                       ei1, ei1 + N_EDGES, v1,
                                                       off, rank, ep, N_EDGES);
        k1_gemm_hist<<<GEMM_BLOCKS, blk, 0, stream>>>(   // gemm blocks only
            x, wt, pre0, pre1, ei0, ei1, cnt, rank, N_NODES, 0);
        gather_fused<<<12500, blk, 0, stream>>>(off, ep, pre0, pre1, out, N_NODES);
    } else {
        // minimal sequential path
        unsigned short* pre = (unsigned short*)wsb;
        unsigned short* wt  = (unsigned short*)(wsb + PRE_B);
        int*  off  = (int*)(wsb + PRE_B + WT_B);
        int*  cnt  = off + (N_NODES + 1);
        int2* ep   = (int2*)(cnt + N_NODES);
        int*  rank = (int*)pre;

        wt_build<<<128, blk, 0, stream>>>(weights, wt);
        const int* rows[2] = {ei0, ei1};
        const int* cols[2] = {ei0 + N_EDGES, ei1 + N_EDGES};
        const float* vals[2] = {v0, v1};
        for (int s = 0; s < 2; ++s) {
            hipMemsetAsync(cnt, 0, (size_t)N_NODES * sizeof(int), stream);
            hist_rank<<<dim3(1024, 1), blk, 0, stream>>>(rows[s], rows[s], cnt, rank, N_EDGES);
            scan_fast<<<1, 1024, 0, stream>>>(cnt, off, N_NODES);
            scatter_csr<<<dim3(1024, 1), blk, 0, stream>>>(rows[s], cols[s], vals[s],
                                                           rows[s], cols[s], vals[s],
                                                           off, rank, ep, N_EDGES);
            gemm_mfma1<<<GEMM_BLOCKS, blk, 0, stream>>>(x, wt + (size_t)s * D * D, pre, N_NODES);
            if (s == 0)
                gather_one<0><<<12500, blk, 0, stream>>>(off, ep, pre, out, N_NODES);
            else
                gather_one<1><<<12500, blk, 0, stream>>>(off, ep, pre, out, N_NODES);
        }
    }
}

// Round 7
// 187.867 us; speedup vs baseline: 1.4427x; 1.4427x over previous
//
#include <hip/hip_runtime.h>

#define N_NODES 50000
#define D 128
#define N_EDGES 800000
#define SCAN_BLOCKS ((N_NODES + 255) / 256)   // 196

typedef __attribute__((ext_vector_type(8))) short short8;
typedef __attribute__((ext_vector_type(4))) float f32x4;

__device__ __forceinline__ unsigned short f2bf(float f) {
    unsigned u = __builtin_bit_cast(unsigned, f);
    u += 0x7FFFu + ((u >> 16) & 1u);
    return (unsigned short)(u >> 16);
}
__device__ __forceinline__ float bflo(unsigned p) {
    return __builtin_bit_cast(float, p << 16);
}
__device__ __forceinline__ float bfhi(unsigned p) {
    return __builtin_bit_cast(float, p & 0xFFFF0000u);
}

#define GEMM_BLOCKS ((N_NODES + 63) / 64)   // 782
#define HIST_VBLOCKS 1024                   // virtual blocks per support

// ---- build wt[s][c][k] bf16 (transposed, c-major) from w[s][k][c] f32 ----
__global__ __launch_bounds__(256) void wt_build(const float* __restrict__ w,
                                                unsigned short* __restrict__ wt) {
    int i = blockIdx.x * 256 + threadIdx.x;
    if (i < 2 * D * D) {
        int s = i >> 14, rem = i & 16383, c = rem >> 7, k = rem & 127;
        wt[i] = f2bf(w[s * D * D + k * D + c]);
    }
}

// ---- gemm body (device fn): pre_s = bf16(x @ W_s) for 64 rows starting r0 ----
template<int NS>
__device__ __forceinline__ void gemm_body(const float* __restrict__ x,
                                          const unsigned short* __restrict__ wt,
                                          unsigned short* __restrict__ pre0,
                                          unsigned short* __restrict__ pre1,
                                          int n_rows, int blk) {
    const int lane = threadIdx.x & 63;
    const int wid  = threadIdx.x >> 6;
    const int q    = lane >> 4;
    const int rlo  = lane & 15;
    const int r0   = blk * 64 + wid * 16;
    if (r0 >= n_rows) return;

    const float4* x4 = (const float4*)x;
    int arow  = r0 + rlo;
    int arowc = arow < n_rows ? arow : n_rows - 1;

    short8 afr[4];
    #pragma unroll
    for (int kb = 0; kb < 4; ++kb) {
        float4 fa = x4[(size_t)arowc * 32 + kb * 8 + q * 2];
        float4 fb = x4[(size_t)arowc * 32 + kb * 8 + q * 2 + 1];
        short8 a;
        a[0] = (short)f2bf(fa.x); a[1] = (short)f2bf(fa.y);
        a[2] = (short)f2bf(fa.z); a[3] = (short)f2bf(fa.w);
        a[4] = (short)f2bf(fb.x); a[5] = (short)f2bf(fb.y);
        a[6] = (short)f2bf(fb.z); a[7] = (short)f2bf(fb.w);
        afr[kb] = a;
    }

    const short8* wt8 = (const short8*)wt;
    f32x4 acc[NS][8];
    #pragma unroll
    for (int s = 0; s < NS; ++s)
        #pragma unroll
        for (int t = 0; t < 8; ++t)
            acc[s][t] = (f32x4){0.f, 0.f, 0.f, 0.f};

    #pragma unroll
    for (int t = 0; t < 8; ++t) {
        int c = t * 16 + rlo;
        #pragma unroll
        for (int kb = 0; kb < 4; ++kb) {
            short8 b0 = wt8[(size_t)c * 16 + kb * 4 + q];
            acc[0][t] = __builtin_amdgcn_mfma_f32_16x16x32_bf16(afr[kb], b0, acc[0][t], 0, 0, 0);
            if (NS == 2) {
                short8 b1 = wt8[(size_t)(D + c) * 16 + kb * 4 + q];
                acc[1][t] = __builtin_amdgcn_mfma_f32_16x16x32_bf16(afr[kb], b1, acc[1][t], 0, 0, 0);
            }
        }
    }

    #pragma unroll
    for (int i = 0; i < 4; ++i) {
        int rw = r0 + q * 4 + i;
        if (rw < n_rows) {
            #pragma unroll
            for (int t = 0; t < 8; ++t) {
                pre0[(size_t)rw * D + t * 16 + rlo] = f2bf(acc[0][t][i]);
                if (NS == 2) pre1[(size_t)rw * D + t * 16 + rlo] = f2bf(acc[1][t][i]);
            }
        }
    }
}

// ---- K1: grid-fused [gemm blocks | hist blocks] (independent work, overlap) ----
__global__ __launch_bounds__(256) void k1_gemm_hist(const float* __restrict__ x,
                                                    const unsigned short* __restrict__ wt,
                                                    unsigned short* __restrict__ pre0,
                                                    unsigned short* __restrict__ pre1,
                                                    const int* __restrict__ r0,
                                                    const int* __restrict__ r1,
                                                    int* __restrict__ cnt_base,
                                                    int* __restrict__ rank_base,
                                                    int n_rows, int n_edges) {
    int bid = blockIdx.x;
    if (bid < GEMM_BLOCKS) {
        gemm_body<2>(x, wt, pre0, pre1, n_rows, bid);
    } else {
        int hb = bid - GEMM_BLOCKS;       // 0 .. 2*HIST_VBLOCKS-1
        int s  = hb & 1;
        int vb = hb >> 1;
        const int* r = s ? r1 : r0;
        int* cnt  = cnt_base + s * N_NODES;
        int* rank = rank_base + (size_t)s * N_EDGES;
        for (int e = vb * 256 + (int)threadIdx.x; e < n_edges; e += HIST_VBLOCKS * 256)
            rank[e] = atomicAdd(&cnt[r[e]], 1);
    }
}

// ---- standalone pieces for fallback paths ----
__global__ __launch_bounds__(256) void gemm_mfma1(const float* __restrict__ x,
                                                  const unsigned short* __restrict__ wt,
                                                  unsigned short* __restrict__ pre,
                                                  int n_rows) {
    gemm_body<1>(x, wt, pre, pre, n_rows, blockIdx.x);
}

__global__ __launch_bounds__(256) void hist_rank(const int* __restrict__ r0,
                                                 const int* __restrict__ r1,
                                                 int* __restrict__ cnt_base,
                                                 int* __restrict__ rank_base, int n_edges) {
    int s = blockIdx.y;
    const int* r = s ? r1 : r0;
    int* cnt  = cnt_base + s * N_NODES;
    int* rank = rank_base + (size_t)s * N_EDGES;
    for (int e = blockIdx.x * 256 + threadIdx.x; e < n_edges; e += gridDim.x * 256)
        rank[e] = atomicAdd(&cnt[r[e]], 1);
}

// ---- 3-phase multi-block scan ----
// A: per-block sums. grid (SCAN_BLOCKS, nsup)
__global__ __launch_bounds__(256) void scanA(const int* __restrict__ cnt_base,
                                             int* __restrict__ bsum) {
    int s = blockIdx.y;
    int i = blockIdx.x * 256 + threadIdx.x;
    int v = (i < N_NODES) ? cnt_base[s * N_NODES + i] : 0;
    const int lane = threadIdx.x & 63;
    const int wid  = threadIdx.x >> 6;
    __shared__ int ws[4];
    #pragma unroll
    for (int off = 32; off > 0; off >>= 1) v += __shfl_down(v, off);
    if (lane == 0) ws[wid] = v;
    __syncthreads();
    if (threadIdx.x == 0)
        bsum[s * SCAN_BLOCKS + blockIdx.x] = ws[0] + ws[1] + ws[2] + ws[3];
}

// B: exclusive-scan the SCAN_BLOCKS sums, in place. grid (nsup)
__global__ __launch_bounds__(256) void scanB(int* __restrict__ bsum) {
    int s = blockIdx.x;
    int t = threadIdx.x;
    int v = (t < SCAN_BLOCKS) ? bsum[s * SCAN_BLOCKS + t] : 0;
    const int lane = t & 63;
    const int wid  = t >> 6;
    __shared__ int ws[4];
    int incl = v;
    #pragma unroll
    for (int off = 1; off < 64; off <<= 1) {
        int tv = __shfl_up(incl, off);
        if (lane >= off) incl += tv;
    }
    if (lane == 63) ws[wid] = incl;
    __syncthreads();
    int wbase = 0;
    #pragma unroll
    for (int j = 0; j < 4; ++j) wbase += (j < wid) ? ws[j] : 0;
    if (t < SCAN_BLOCKS) bsum[s * SCAN_BLOCKS + t] = wbase + incl - v;
}

// C: block-local exclusive scan + block base -> offsets. grid (SCAN_BLOCKS, nsup)
__global__ __launch_bounds__(256) void scanC(const int* __restrict__ cnt_base,
                                             const int* __restrict__ bsum,
                                             int* __restrict__ off_base) {
    int s = blockIdx.y;
    int i = blockIdx.x * 256 + threadIdx.x;
    int v = (i < N_NODES) ? cnt_base[s * N_NODES + i] : 0;
    const int lane = threadIdx.x & 63;
    const int wid  = threadIdx.x >> 6;
    __shared__ int ws[4];
    int incl = v;
    #pragma unroll
    for (int off = 1; off < 64; off <<= 1) {
        int tv = __shfl_up(incl, off);
        if (lane >= off) incl += tv;
    }
    if (lane == 63) ws[wid] = incl;
    __syncthreads();
    int wbase = 0;
    #pragma unroll
    for (int j = 0; j < 4; ++j) wbase += (j < wid) ? ws[j] : 0;
    int* off = off_base + s * (N_NODES + 1);
    if (i < N_NODES)
        off[i] = bsum[s * SCAN_BLOCKS + blockIdx.x] + wbase + incl - v;
    if (blockIdx.x == 0 && threadIdx.x == 0)
        off[N_NODES] = N_EDGES;   // total edges per support is fixed
}

// ---- CSR scatter: no atomics, fire-and-forget 8B stores (y-dim = support) ----
__global__ __launch_bounds__(256) void scatter_csr(const int* __restrict__ r0, const int* __restrict__ c0,
                                                   const float* __restrict__ v0,
                                                   const int* __restrict__ r1, const int* __restrict__ c1,
                                                   const float* __restrict__ v1,
                                                   const int* __restrict__ off_base,
                                                   const int* __restrict__ rank_base,
                                                   int2* __restrict__ ep_base, int n_edges) {
    int s = blockIdx.y;
    const int*   r    = s ? r1 : r0;
    const int*   c    = s ? c1 : c0;
    const float* v    = s ? v1 : v0;
    const int*   off  = off_base + s * (N_NODES + 1);
    const int*   rank = rank_base + (size_t)s * N_EDGES;
    int2* ep = ep_base + (size_t)s * N_EDGES;
    for (int e = blockIdx.x * 256 + threadIdx.x; e < n_edges; e += gridDim.x * 256) {
        int p = off[r[e]] + rank[e];
        int2 rec;
        rec.x = c[e];
        rec.y = __float_as_int(v[e]);
        ep[p] = rec;
    }
}

// ---- row accumulate: unroll-8 pipelined random reads ----
__device__ __forceinline__ void row_acc(const int2* __restrict__ ep,
                                        const unsigned short* __restrict__ pre,
                                        int b, int e, int lane, float& ax, float& ay) {
    int i = b;
    for (; i + 7 < e; i += 8) {
        int2 E[8];
        unsigned P[8];
        #pragma unroll
        for (int j = 0; j < 8; ++j) E[j] = ep[i + j];
        #pragma unroll
        for (int j = 0; j < 8; ++j) P[j] = *(const unsigned*)(pre + (size_t)E[j].x * D + 2 * lane);
        #pragma unroll
        for (int j = 0; j < 8; ++j) {
            float w = __int_as_float(E[j].y);
            ax = fmaf(w, bflo(P[j]), ax);
            ay = fmaf(w, bfhi(P[j]), ay);
        }
    }
    if (i + 3 < e) {
        int2 E[4];
        unsigned P[4];
        #pragma unroll
        for (int j = 0; j < 4; ++j) E[j] = ep[i + j];
        #pragma unroll
        for (int j = 0; j < 4; ++j) P[j] = *(const unsigned*)(pre + (size_t)E[j].x * D + 2 * lane);
        #pragma unroll
        for (int j = 0; j < 4; ++j) {
            float w = __int_as_float(E[j].y);
            ax = fmaf(w, bflo(P[j]), ax);
            ay = fmaf(w, bfhi(P[j]), ay);
        }
        i += 4;
    }
    for (; i < e; ++i) {
        int2 e0 = ep[i];
        float w = __int_as_float(e0.y);
        unsigned p = *(const unsigned*)(pre + (size_t)e0.x * D + 2 * lane);
        ax = fmaf(w, bflo(p), ax);
        ay = fmaf(w, bfhi(p), ay);
    }
}

// ---- fused gather: out = relu(A0@pre0 + A1@pre1), one wave per row ----
__global__ __launch_bounds__(256) void gather_fused(const int* __restrict__ off_base,
                                                    const int2* __restrict__ ep_base,
                                                    const unsigned short* __restrict__ pre0,
                                                    const unsigned short* __restrict__ pre1,
                                                    float* __restrict__ out, int n_rows) {
    const int lane = threadIdx.x & 63;
    const int wid  = threadIdx.x >> 6;
    const int wpg  = 4 * gridDim.x;
    float2* out2 = (float2*)out;
    for (int r = blockIdx.x * 4 + wid; r < n_rows; r += wpg) {
        float ax0 = 0.f, ay0 = 0.f, ax1 = 0.f, ay1 = 0.f;
        row_acc(ep_base, pre0, off_base[r], off_base[r + 1], lane, ax0, ay0);
        const int* o1 = off_base + (N_NODES + 1);
        row_acc(ep_base + N_EDGES, pre1, o1[r], o1[r + 1], lane, ax1, ay1);
        float2 o;
        o.x = fmaxf(ax0 + ax1, 0.f);
        o.y = fmaxf(ay0 + ay1, 0.f);
        out2[(size_t)r * 64 + lane] = o;
    }
}

// ---- single-support gather (sequential fallback) ----
template<int ACCUM_RELU>
__global__ __launch_bounds__(256) void gather_one(const int* __restrict__ off,
                                                  const int2* __restrict__ ep,
                                                  const unsigned short* __restrict__ pre,
                                                  float* __restrict__ out, int n_rows) {
    const int lane = threadIdx.x & 63;
    const int wid  = threadIdx.x >> 6;
    const int wpg  = 4 * gridDim.x;
    float2* out2 = (float2*)out;
    for (int r = blockIdx.x * 4 + wid; r < n_rows; r += wpg) {
        float ax = 0.f, ay = 0.f;
        row_acc(ep, pre, off[r], off[r + 1], lane, ax, ay);
        float2 o;
        if (ACCUM_RELU) {
            float2 prev = out2[(size_t)r * 64 + lane];
            o.x = fmaxf(prev.x + ax, 0.f);
            o.y = fmaxf(prev.y + ay, 0.f);
        } else {
            o.x = ax; o.y = ay;
        }
        out2[(size_t)r * 64 + lane] = o;
    }
}

extern "C" void kernel_launch(void* const* d_in, const int* in_sizes, int n_in,
                              void* d_out, int out_size, void* d_ws, size_t ws_size,
                              hipStream_t stream) {
    const float* x       = (const float*)d_in[0];
    const float* weights = (const float*)d_in[1];
    const int*   ei0     = (const int*)d_in[2];
    const float* v0      = (const float*)d_in[3];
    const int*   ei1     = (const int*)d_in[4];
    const float* v1      = (const float*)d_in[5];
    float* out = (float*)d_out;

    dim3 blk(256);
    const size_t PRE_B = (size_t)N_NODES * D * sizeof(unsigned short);  // 12.8 MB
    const size_t WT_B  = (size_t)2 * D * D * sizeof(unsigned short);    // 64 KB

    char* wsb = (char*)d_ws;
    // tier A: pre0, pre1, wt, off[2(N+1)], cnt[2N], bsum[2*SB], ep[2E], rank[2E]
    size_t needA = PRE_B * 2 + WT_B
                 + (size_t)(2 * (N_NODES + 1) + 2 * N_NODES + 2 * SCAN_BLOCKS) * 4
                 + (size_t)2 * N_EDGES * sizeof(int2) + (size_t)2 * N_EDGES * 4;
    // tier B: same minus rank (rank aliases pre0, serial schedule)
    size_t needB = needA - (size_t)2 * N_EDGES * 4;

    if (ws_size >= needA) {
        unsigned short* pre0 = (unsigned short*)wsb;
        unsigned short* pre1 = (unsigned short*)(wsb + PRE_B);
        unsigned short* wt   = (unsigned short*)(wsb + 2 * PRE_B);
        int*  off  = (int*)(wsb + 2 * PRE_B + WT_B);
        int*  cnt  = off + 2 * (N_NODES + 1);
        int*  bsum = cnt + 2 * N_NODES;
        int2* ep   = (int2*)(bsum + 2 * SCAN_BLOCKS);
        int*  rank = (int*)(ep + (size_t)2 * N_EDGES);

        hipMemsetAsync(cnt, 0, (size_t)2 * N_NODES * sizeof(int), stream);
        wt_build<<<128, blk, 0, stream>>>(weights, wt);
        k1_gemm_hist<<<GEMM_BLOCKS + 2 * HIST_VBLOCKS, blk, 0, stream>>>(
            x, wt, pre0, pre1, ei0, ei1, cnt, rank, N_NODES, N_EDGES);
        scanA<<<dim3(SCAN_BLOCKS, 2), blk, 0, stream>>>(cnt, bsum);
        scanB<<<2, blk, 0, stream>>>(bsum);
        scanC<<<dim3(SCAN_BLOCKS, 2), blk, 0, stream>>>(cnt, bsum, off);
        scatter_csr<<<dim3(1024, 2), blk, 0, stream>>>(ei0, ei0 + N_EDGES, v0,
                                                       ei1, ei1 + N_EDGES, v1,
                                                       off, rank, ep, N_EDGES);
        gather_fused<<<12500, blk, 0, stream>>>(off, ep, pre0, pre1, out, N_NODES);
    } else if (ws_size >= needB) {
        unsigned short* pre0 = (unsigned short*)wsb;
        unsigned short* pre1 = (unsigned short*)(wsb + PRE_B);
        unsigned short* wt   = (unsigned short*)(wsb + 2 * PRE_B);
        int*  off  = (int*)(wsb + 2 * PRE_B + WT_B);
        int*  cnt  = off + 2 * (N_NODES + 1);
        int*  bsum = cnt + 2 * N_NODES;
        int2* ep   = (int2*)(bsum + 2 * SCAN_BLOCKS);
        int*  rank = (int*)pre0;   // aliases pre0; serial: scatter before gemm

        hipMemsetAsync(cnt, 0, (size_t)2 * N_NODES * sizeof(int), stream);
        wt_build<<<128, blk, 0, stream>>>(weights, wt);
        hist_rank<<<dim3(1024, 2), blk, 0, stream>>>(ei0, ei1, cnt, rank, N_EDGES);
        scanA<<<dim3(SCAN_BLOCKS, 2), blk, 0, stream>>>(cnt, bsum);
        scanB<<<2, blk, 0, stream>>>(bsum);
        scanC<<<dim3(SCAN_BLOCKS, 2), blk, 0, stream>>>(cnt, bsum, off);
        scatter_csr<<<dim3(1024, 2), blk, 0, stream>>>(ei0, ei0 + N_EDGES, v0,
                                                       ei1, ei1 + N_EDGES, v1,
                                                       off, rank, ep, N_EDGES);
        k1_gemm_hist<<<GEMM_BLOCKS, blk, 0, stream>>>(   // gemm blocks only
            x, wt, pre0, pre1, ei0, ei1, cnt, rank, N_NODES, 0);
        gather_fused<<<12500, blk, 0, stream>>>(off, ep, pre0, pre1, out, N_NODES);
    } else {
        // minimal sequential path
        unsigned short* pre = (unsigned short*)wsb;
        unsigned short* wt  = (unsigned short*)(wsb + PRE_B);
        int*  off  = (int*)(wsb + PRE_B + WT_B);
        int*  cnt  = off + (N_NODES + 1);
        int*  bsum = cnt + N_NODES;
        int2* ep   = (int2*)(bsum + SCAN_BLOCKS);
        int*  rank = (int*)pre;

        wt_build<<<128, blk, 0, stream>>>(weights, wt);
        const int* rows[2] = {ei0, ei1};
        const int* cols[2] = {ei0 + N_EDGES, ei1 + N_EDGES};
        const float* vals[2] = {v0, v1};
        for (int s = 0; s < 2; ++s) {
            hipMemsetAsync(cnt, 0, (size_t)N_NODES * sizeof(int), stream);
            hist_rank<<<dim3(1024, 1), blk, 0, stream>>>(rows[s], rows[s], cnt, rank, N_EDGES);
            scanA<<<dim3(SCAN_BLOCKS, 1), blk, 0, stream>>>(cnt, bsum);
            scanB<<<1, blk, 0, stream>>>(bsum);
            scanC<<<dim3(SCAN_BLOCKS, 1), blk, 0, stream>>>(cnt, bsum, off);
            scatter_csr<<<dim3(1024, 1), blk, 0, stream>>>(rows[s], cols[s], vals[s],
                                                           rows[s], cols[s], vals[s],
                                                           off, rank, ep, N_EDGES);
            gemm_mfma1<<<GEMM_BLOCKS, blk, 0, stream>>>(x, wt + (size_t)s * D * D, pre, N_NODES);
            if (s == 0)
                gather_one<0><<<12500, blk, 0, stream>>>(off, ep, pre, out, N_NODES);
            else
                gather_one<1><<<12500, blk, 0, stream>>>(off, ep, pre, out, N_NODES);
        }
    }
}